// Round 2
// baseline (305.770 us; speedup 1.0000x reference)
//
#include <hip/hip_runtime.h>

#define NTOK 16384
#define DIM 512
#define NTAU 4

typedef __attribute__((ext_vector_type(4))) float f32x4;
typedef __attribute__((ext_vector_type(8))) short bf16x8;   // 8 bf16 in 4 VGPRs
typedef __attribute__((ext_vector_type(4))) unsigned short u16x4;
typedef __attribute__((ext_vector_type(8))) unsigned short u16x8;

__device__ inline unsigned short f2bf(float f) {
    union { float f; unsigned int u; } v; v.f = f;
    unsigned int u = v.u + 0x7FFFu + ((v.u >> 16) & 1u);  // RNE
    return (unsigned short)(u >> 16);
}

__device__ inline void bf8_to_f32(u16x8 h, f32x4& a, f32x4& b) {
    union { unsigned int u; float f; } t;
#pragma unroll
    for (int e = 0; e < 4; e++) { t.u = ((unsigned int)h[e]) << 16; a[e] = t.f; }
#pragma unroll
    for (int e = 0; e < 4; e++) { t.u = ((unsigned int)h[4 + e]) << 16; b[e] = t.f; }
}

#define NTLOAD4(p) __builtin_nontemporal_load((const f32x4*)(p))

// ---------------- K0: fp32 -> bf16 convert (weights) ----------------
__global__ void convert_f32_bf16(const float* __restrict__ src,
                                 unsigned short* __restrict__ dst, int n4) {
    int i = blockIdx.x * blockDim.x + threadIdx.x;
    if (i < n4) {
        f32x4 v = ((const f32x4*)src)[i];
        u16x4 o;
        o[0] = f2bf(v[0]); o[1] = f2bf(v[1]); o[2] = f2bf(v[2]); o[3] = f2bf(v[3]);
        ((u16x4*)dst)[i] = o;
    }
}

// ---------------- K1: next = A @ W^T + b  -> bf16 out ----------------
// BM=128 BN=128 BK=32, 256 thr = 4 waves (2x2), wave computes 64x64 (4x4 frags)
__global__ __launch_bounds__(256, 2) void gemm_next(
    const float* __restrict__ A, const unsigned short* __restrict__ W,
    const float* __restrict__ bias, unsigned short* __restrict__ out)
{
    __shared__ unsigned short lA[128][40];
    __shared__ unsigned short lB[128][40];
    const int tid = threadIdx.x;
    const int m0 = blockIdx.y * 128;
    const int n0 = blockIdx.x * 128;
    const int lane = tid & 63;
    const int w = tid >> 6;
    const int wr = w >> 1, wc = w & 1;

    f32x4 acc[4][4];
#pragma unroll
    for (int i = 0; i < 4; i++)
#pragma unroll
        for (int j = 0; j < 4; j++) acc[i][j] = (f32x4){0.f, 0.f, 0.f, 0.f};

    const int arow = tid >> 3;         // 0..31
    const int acol = (tid & 7) * 4;    // fp32 col within tile
    const int brow = tid >> 2;         // 0..63
    const int bcol = (tid & 3) * 8;    // bf16 col within tile

    for (int k0 = 0; k0 < DIM; k0 += 32) {
#pragma unroll
        for (int i = 0; i < 4; i++) {
            int r = arow + 32 * i;
            f32x4 v = *(const f32x4*)(A + (size_t)(m0 + r) * DIM + k0 + acol);
            u16x4 o;
            o[0] = f2bf(v[0]); o[1] = f2bf(v[1]); o[2] = f2bf(v[2]); o[3] = f2bf(v[3]);
            *(u16x4*)&lA[r][acol] = o;
        }
#pragma unroll
        for (int i = 0; i < 2; i++) {
            int r = brow + 64 * i;
            u16x8 v = *(const u16x8*)(W + (size_t)(n0 + r) * DIM + k0 + bcol);
            *(u16x8*)&lB[r][bcol] = v;
        }
        __syncthreads();

        bf16x8 af[4], bfr[4];
#pragma unroll
        for (int i = 0; i < 4; i++)
            af[i] = *(const bf16x8*)&lA[wr * 64 + i * 16 + (lane & 15)][(lane >> 4) * 8];
#pragma unroll
        for (int j = 0; j < 4; j++)
            bfr[j] = *(const bf16x8*)&lB[wc * 64 + j * 16 + (lane & 15)][(lane >> 4) * 8];
#pragma unroll
        for (int i = 0; i < 4; i++)
#pragma unroll
            for (int j = 0; j < 4; j++)
                acc[i][j] = __builtin_amdgcn_mfma_f32_16x16x32_bf16(af[i], bfr[j], acc[i][j], 0, 0, 0);
        __syncthreads();
    }

#pragma unroll
    for (int j = 0; j < 4; j++) {
        int n = n0 + wc * 64 + j * 16 + (lane & 15);
        float bv = bias[n];
#pragma unroll
        for (int i = 0; i < 4; i++) {
            int mbase = m0 + wr * 64 + i * 16 + (lane >> 4) * 4;
#pragma unroll
            for (int r = 0; r < 4; r++)
                out[(size_t)(mbase + r) * DIM + n] = f2bf(acc[i][j][r] + bv);
        }
    }
}

// ---------------- K2: streaming fuse (dots, softmax, trend, gates) ----------------
// One wave handles tokens 2w, 2w+1; attention tensors via non-temporal loads.
__global__ __launch_bounds__(256) void fuse_stream(
    const float* __restrict__ T_t, const float* __restrict__ S_t,
    const float* __restrict__ t_att, const float* __restrict__ s_att,
    const float* __restrict__ t_spatial, const float* __restrict__ s_spatial,
    const unsigned short* __restrict__ t_next, const unsigned short* __restrict__ s_next,
    unsigned short* __restrict__ Tf, unsigned short* __restrict__ Sf)
{
    const int lane = threadIdx.x & 63;
    const int w = blockIdx.x * 4 + (threadIdx.x >> 6);
    const float scale = 0.04419417382415922f;  // 1/sqrt(512)
    const int c = lane * 8;

    const int n[2] = { 2 * w, 2 * w + 1 };
    f32x4 tn_a[2], tn_b[2], sn_a[2], sn_b[2];
#pragma unroll
    for (int t = 0; t < 2; t++) {
        const size_t rb = (size_t)n[t] * DIM + c;
        bf8_to_f32(*(const u16x8*)(t_next + rb), tn_a[t], tn_b[t]);
        bf8_to_f32(*(const u16x8*)(s_next + rb), sn_a[t], sn_b[t]);
    }

    // ---- phase 1: dot products (s_att . s_next), (t_spatial . t_next) ----
    float dws[2][NTAU], dwt[2][NTAU];
#pragma unroll
    for (int t = 0; t < 2; t++) {
#pragma unroll
        for (int k = 0; k < NTAU; k++) {
            const size_t kb = ((size_t)k * NTOK + n[t]) * DIM + c;
            f32x4 sa = NTLOAD4(s_att + kb);
            f32x4 sb = NTLOAD4(s_att + kb + 4);
            f32x4 ta = NTLOAD4(t_spatial + kb);
            f32x4 tb = NTLOAD4(t_spatial + kb + 4);
            dws[t][k] = sa[0]*sn_a[t][0]+sa[1]*sn_a[t][1]+sa[2]*sn_a[t][2]+sa[3]*sn_a[t][3]
                      + sb[0]*sn_b[t][0]+sb[1]*sn_b[t][1]+sb[2]*sn_b[t][2]+sb[3]*sn_b[t][3];
            dwt[t][k] = ta[0]*tn_a[t][0]+ta[1]*tn_a[t][1]+ta[2]*tn_a[t][2]+ta[3]*tn_a[t][3]
                      + tb[0]*tn_b[t][0]+tb[1]*tn_b[t][1]+tb[2]*tn_b[t][2]+tb[3]*tn_b[t][3];
        }
    }
#pragma unroll
    for (int t = 0; t < 2; t++)
#pragma unroll
        for (int k = 0; k < NTAU; k++) {
            float v = dws[t][k];
#pragma unroll
            for (int off = 32; off; off >>= 1) v += __shfl_xor(v, off);
            dws[t][k] = v * scale;
            float u = dwt[t][k];
#pragma unroll
            for (int off = 32; off; off >>= 1) u += __shfl_xor(u, off);
            dwt[t][k] = u * scale;
        }

    float ws_[2][NTAU], wt_[2][NTAU];
#pragma unroll
    for (int t = 0; t < 2; t++) {
        float ms = fmaxf(fmaxf(dws[t][0], dws[t][1]), fmaxf(dws[t][2], dws[t][3]));
        float mt = fmaxf(fmaxf(dwt[t][0], dwt[t][1]), fmaxf(dwt[t][2], dwt[t][3]));
        float ssum = 0.f, tsum = 0.f;
#pragma unroll
        for (int k = 0; k < NTAU; k++) {
            ws_[t][k] = __expf(dws[t][k] - ms); ssum += ws_[t][k];
            wt_[t][k] = __expf(dwt[t][k] - mt); tsum += wt_[t][k];
        }
        float rs = 1.f / ssum, rt = 1.f / tsum;
#pragma unroll
        for (int k = 0; k < NTAU; k++) { ws_[t][k] *= rs; wt_[t][k] *= rt; }
    }

    // ---- phase 2: trend accumulation + gating ----
#pragma unroll
    for (int t = 0; t < 2; t++) {
        const size_t rb = (size_t)n[t] * DIM + c;
        f32x4 Tta = {0,0,0,0}, Ttb = {0,0,0,0}, Sta = {0,0,0,0}, Stb = {0,0,0,0};
#pragma unroll
        for (int k = 0; k < NTAU; k++) {
            const size_t kb = ((size_t)k * NTOK + n[t]) * DIM + c;
            f32x4 ta = NTLOAD4(t_att + kb);
            f32x4 tb = NTLOAD4(t_att + kb + 4);
            f32x4 sa = NTLOAD4(s_spatial + kb);
            f32x4 sb = NTLOAD4(s_spatial + kb + 4);
            float wk = ws_[t][k], vk = wt_[t][k];
#pragma unroll
            for (int e = 0; e < 4; e++) {
                Tta[e] += wk * ta[e]; Ttb[e] += wk * tb[e];
                Sta[e] += vk * sa[e]; Stb[e] += vk * sb[e];
            }
        }
        f32x4 Ta = *(const f32x4*)(T_t + rb);
        f32x4 Tb = *(const f32x4*)(T_t + rb + 4);
        f32x4 Sa = *(const f32x4*)(S_t + rb);
        f32x4 Sb = *(const f32x4*)(S_t + rb + 4);

        u16x8 oT, oS;
#pragma unroll
        for (int e = 0; e < 4; e++) {
            float gt_a = 1.f / (1.f + __expf(-tn_a[t][e]));
            float gt_b = 1.f / (1.f + __expf(-tn_b[t][e]));
            float gs_a = 1.f / (1.f + __expf(-sn_a[t][e]));
            float gs_b = 1.f / (1.f + __expf(-sn_b[t][e]));
            oT[e]     = f2bf(Ta[e] * gt_a + (1.f - gt_a) * Tta[e]);
            oT[4 + e] = f2bf(Tb[e] * gt_b + (1.f - gt_b) * Ttb[e]);
            oS[e]     = f2bf(Sa[e] * gs_a + (1.f - gs_a) * Sta[e]);
            oS[4 + e] = f2bf(Sb[e] * gs_b + (1.f - gs_b) * Stb[e]);
        }
        *(u16x8*)(Tf + rb) = oT;
        *(u16x8*)(Sf + rb) = oS;
    }
}

// ---------------- K3: fused final GEMM + epilogue -> d_out ----------------
__global__ __launch_bounds__(256, 2) void gemm_final(
    const unsigned short* __restrict__ Tf, const unsigned short* __restrict__ Sf,
    const unsigned short* __restrict__ Wt, const unsigned short* __restrict__ Ws,
    const float* __restrict__ bt, const float* __restrict__ bs,
    float* __restrict__ out)
{
    __shared__ unsigned short lT[128][40];
    __shared__ unsigned short lS[128][40];
    __shared__ unsigned short lW[6][32][40];
    const int tid = threadIdx.x;
    const int m0 = blockIdx.y * 128;
    const int j0 = blockIdx.x * 32;
    const int lane = tid & 63;
    const int w = tid >> 6, wr = w >> 1, wc = w & 1;

    f32x4 acc[6][4];
#pragma unroll
    for (int g = 0; g < 6; g++)
#pragma unroll
        for (int i = 0; i < 4; i++) acc[g][i] = (f32x4){0.f, 0.f, 0.f, 0.f};

    const int arow = tid >> 2;        // 0..63
    const int acol = (tid & 3) * 8;   // bf16 col

    for (int k0 = 0; k0 < DIM; k0 += 32) {
#pragma unroll
        for (int i = 0; i < 2; i++) {
            int r = arow + 64 * i;
            *(u16x8*)&lT[r][acol] = *(const u16x8*)(Tf + (size_t)(m0 + r) * DIM + k0 + acol);
            *(u16x8*)&lS[r][acol] = *(const u16x8*)(Sf + (size_t)(m0 + r) * DIM + k0 + acol);
        }
#pragma unroll
        for (int i = 0; i < 3; i++) {
            int cidx = tid + 256 * i;       // 0..767
            int g = cidx >> 7;              // 6 tiles of 128 chunks
            int rr = (cidx >> 2) & 31;
            int ch = (cidx & 3) * 8;
            const unsigned short* src = (g < 3) ? Wt : Ws;
            int row = (g % 3) * DIM + j0 + rr;
            *(u16x8*)&lW[g][rr][ch] = *(const u16x8*)(src + (size_t)row * DIM + k0 + ch);
        }
        __syncthreads();

        bf16x8 aT[4], aS[4];
#pragma unroll
        for (int i = 0; i < 4; i++) {
            aT[i] = *(const bf16x8*)&lT[wr * 64 + i * 16 + (lane & 15)][(lane >> 4) * 8];
            aS[i] = *(const bf16x8*)&lS[wr * 64 + i * 16 + (lane & 15)][(lane >> 4) * 8];
        }
#pragma unroll
        for (int g = 0; g < 6; g++) {
            bf16x8 bw = *(const bf16x8*)&lW[g][wc * 16 + (lane & 15)][(lane >> 4) * 8];
#pragma unroll
            for (int i = 0; i < 4; i++)
                acc[g][i] = __builtin_amdgcn_mfma_f32_16x16x32_bf16(
                    (g < 3) ? aT[i] : aS[i], bw, acc[g][i], 0, 0, 0);
        }
        __syncthreads();
    }

    const int j = j0 + wc * 16 + (lane & 15);
    const float btg = bt[j], btt = bt[512 + j], bts = bt[1024 + j];
    const float bsg = bs[j], bst = bs[512 + j], bss = bs[1024 + j];
#pragma unroll
    for (int i = 0; i < 4; i++) {
        int mbase = m0 + wr * 64 + i * 16 + (lane >> 4) * 4;
#pragma unroll
        for (int r = 0; r < 4; r++) {
            float TG = acc[0][i][r] + btg;
            float TT = acc[1][i][r] + btt;
            float TS = acc[2][i][r] + bts;
            float SG = acc[3][i][r] + bsg;
            float ST = acc[4][i][r] + bst;
            float SS = acc[5][i][r] + bss;
            float gT = 1.f / (1.f + __expf(-TG));
            float gS = 1.f / (1.f + __expf(-SG));
            size_t m = (size_t)(mbase + r);
            out[m * DIM + j] = gT * TT + (1.f - gT) * ST;
            out[(size_t)NTOK * DIM + m * DIM + j] = gS * SS + (1.f - gS) * TS;
        }
    }
}

extern "C" void kernel_launch(void* const* d_in, const int* in_sizes, int n_in,
                              void* d_out, int out_size, void* d_ws, size_t ws_size,
                              hipStream_t stream) {
    const float* T_t       = (const float*)d_in[0];
    const float* S_t       = (const float*)d_in[1];
    const float* t_att     = (const float*)d_in[2];
    const float* s_att     = (const float*)d_in[3];
    const float* t_spatial = (const float*)d_in[4];
    const float* s_spatial = (const float*)d_in[5];
    const float* W_t  = (const float*)d_in[6];
    const float* b_t  = (const float*)d_in[7];
    const float* W_tn = (const float*)d_in[8];
    const float* b_tn = (const float*)d_in[9];
    const float* W_s  = (const float*)d_in[10];
    const float* b_s  = (const float*)d_in[11];
    const float* W_sn = (const float*)d_in[12];
    const float* b_sn = (const float*)d_in[13];
    float* out = (float*)d_out;

    char* ws = (char*)d_ws;
    unsigned short* t_next = (unsigned short*)(ws + 0);          // 16.8 MB
    unsigned short* s_next = (unsigned short*)(ws + 16777216);
    unsigned short* Tf     = (unsigned short*)(ws + 33554432);
    unsigned short* Sf     = (unsigned short*)(ws + 50331648);
    unsigned short* Wtn_b  = (unsigned short*)(ws + 67108864);
    unsigned short* Wsn_b  = (unsigned short*)(ws + 67633152);
    unsigned short* Wt_b   = (unsigned short*)(ws + 68157440);
    unsigned short* Ws_b   = (unsigned short*)(ws + 69730304);

    const int n_sq = 512 * 512 / 4, n_big = 1536 * 512 / 4;
    convert_f32_bf16<<<(n_sq + 255) / 256, 256, 0, stream>>>(W_tn, Wtn_b, n_sq);
    convert_f32_bf16<<<(n_sq + 255) / 256, 256, 0, stream>>>(W_sn, Wsn_b, n_sq);
    convert_f32_bf16<<<(n_big + 255) / 256, 256, 0, stream>>>(W_t, Wt_b, n_big);
    convert_f32_bf16<<<(n_big + 255) / 256, 256, 0, stream>>>(W_s, Ws_b, n_big);

    dim3 g1(DIM / 128, NTOK / 128);
    gemm_next<<<g1, 256, 0, stream>>>(T_t, Wtn_b, b_tn, t_next);
    gemm_next<<<g1, 256, 0, stream>>>(S_t, Wsn_b, b_sn, s_next);

    fuse_stream<<<2048, 256, 0, stream>>>(T_t, S_t, t_att, s_att, t_spatial, s_spatial,
                                          t_next, s_next, Tf, Sf);

    dim3 g3(DIM / 32, NTOK / 128);
    gemm_final<<<g3, 256, 0, stream>>>(Tf, Sf, Wt_b, Ws_b, b_t, b_s, out);
}

// Round 3
// 292.465 us; speedup vs baseline: 1.0455x; 1.0455x over previous
//
#include <hip/hip_runtime.h>

#define NTOK 16384
#define DIM 512
#define NTAU 4

typedef __attribute__((ext_vector_type(4))) float f32x4;
typedef __attribute__((ext_vector_type(8))) short bf16x8;   // 8 bf16 in 4 VGPRs
typedef __attribute__((ext_vector_type(4))) unsigned short u16x4;
typedef __attribute__((ext_vector_type(8))) unsigned short u16x8;

__device__ inline unsigned short f2bf(float f) {
    union { float f; unsigned int u; } v; v.f = f;
    unsigned int u = v.u + 0x7FFFu + ((v.u >> 16) & 1u);  // RNE
    return (unsigned short)(u >> 16);
}

__device__ inline void bf8_to_f32(u16x8 h, f32x4& a, f32x4& b) {
    union { unsigned int u; float f; } t;
#pragma unroll
    for (int e = 0; e < 4; e++) { t.u = ((unsigned int)h[e]) << 16; a[e] = t.f; }
#pragma unroll
    for (int e = 0; e < 4; e++) { t.u = ((unsigned int)h[4 + e]) << 16; b[e] = t.f; }
}

#define NTLOAD4(p) __builtin_nontemporal_load((const f32x4*)(p))

// ---------------- K0: fp32 -> bf16 convert (weights) ----------------
__global__ void convert_f32_bf16(const float* __restrict__ src,
                                 unsigned short* __restrict__ dst, int n4) {
    int i = blockIdx.x * blockDim.x + threadIdx.x;
    if (i < n4) {
        f32x4 v = ((const f32x4*)src)[i];
        u16x4 o;
        o[0] = f2bf(v[0]); o[1] = f2bf(v[1]); o[2] = f2bf(v[2]); o[3] = f2bf(v[3]);
        ((u16x4*)dst)[i] = o;
    }
}

// ---------------- K1: next = A @ W^T + b  -> bf16 out ----------------
// BM=128 BN=128 BK=32, 256 thr = 4 waves (2x2); XCD-locality swizzle:
// grid = 512 blocks (4 j x 128 m); each XCD owns 16 contiguous m-stripes.
__global__ __launch_bounds__(256, 2) void gemm_next(
    const float* __restrict__ A, const unsigned short* __restrict__ W,
    const float* __restrict__ bias, unsigned short* __restrict__ out)
{
    __shared__ unsigned short lA[128][40];
    __shared__ unsigned short lB[128][40];
    const int tid = threadIdx.x;
    const int id = blockIdx.x + 4 * blockIdx.y;   // dispatch-linear, 0..511
    const int xcd = id & 7;
    const int idx = id >> 3;                      // 0..63
    const int m0 = (xcd * 16 + (idx >> 2)) * 128;
    const int n0 = (idx & 3) * 128;
    const int lane = tid & 63;
    const int w = tid >> 6;
    const int wr = w >> 1, wc = w & 1;

    f32x4 acc[4][4];
#pragma unroll
    for (int i = 0; i < 4; i++)
#pragma unroll
        for (int j = 0; j < 4; j++) acc[i][j] = (f32x4){0.f, 0.f, 0.f, 0.f};

    const int arow = tid >> 3;         // 0..31
    const int acol = (tid & 7) * 4;    // fp32 col within tile
    const int brow = tid >> 2;         // 0..63
    const int bcol = (tid & 3) * 8;    // bf16 col within tile

    for (int k0 = 0; k0 < DIM; k0 += 32) {
#pragma unroll
        for (int i = 0; i < 4; i++) {
            int r = arow + 32 * i;
            f32x4 v = *(const f32x4*)(A + (size_t)(m0 + r) * DIM + k0 + acol);
            u16x4 o;
            o[0] = f2bf(v[0]); o[1] = f2bf(v[1]); o[2] = f2bf(v[2]); o[3] = f2bf(v[3]);
            *(u16x4*)&lA[r][acol] = o;
        }
#pragma unroll
        for (int i = 0; i < 2; i++) {
            int r = brow + 64 * i;
            u16x8 v = *(const u16x8*)(W + (size_t)(n0 + r) * DIM + k0 + bcol);
            *(u16x8*)&lB[r][bcol] = v;
        }
        __syncthreads();

        bf16x8 af[4], bfr[4];
#pragma unroll
        for (int i = 0; i < 4; i++)
            af[i] = *(const bf16x8*)&lA[wr * 64 + i * 16 + (lane & 15)][(lane >> 4) * 8];
#pragma unroll
        for (int j = 0; j < 4; j++)
            bfr[j] = *(const bf16x8*)&lB[wc * 64 + j * 16 + (lane & 15)][(lane >> 4) * 8];
#pragma unroll
        for (int i = 0; i < 4; i++)
#pragma unroll
            for (int j = 0; j < 4; j++)
                acc[i][j] = __builtin_amdgcn_mfma_f32_16x16x32_bf16(af[i], bfr[j], acc[i][j], 0, 0, 0);
        __syncthreads();
    }

#pragma unroll
    for (int j = 0; j < 4; j++) {
        int n = n0 + wc * 64 + j * 16 + (lane & 15);
        float bv = bias[n];
#pragma unroll
        for (int i = 0; i < 4; i++) {
            int mbase = m0 + wr * 64 + i * 16 + (lane >> 4) * 4;
#pragma unroll
            for (int r = 0; r < 4; r++)
                out[(size_t)(mbase + r) * DIM + n] = f2bf(acc[i][j][r] + bv);
        }
    }
}

// ---------------- K2: streaming fuse (dots, softmax, trend, gates) ----------------
// One wave = one token. Phase-2 loads issued BEFORE the shuffle reduce so the
// serial reduce/softmax window overlaps in-flight memory.
__global__ __launch_bounds__(256) void fuse_stream(
    const float* __restrict__ T_t, const float* __restrict__ S_t,
    const float* __restrict__ t_att, const float* __restrict__ s_att,
    const float* __restrict__ t_spatial, const float* __restrict__ s_spatial,
    const unsigned short* __restrict__ t_next, const unsigned short* __restrict__ s_next,
    unsigned short* __restrict__ Tf, unsigned short* __restrict__ Sf)
{
    const int lane = threadIdx.x & 63;
    const int n = (blockIdx.x << 2) + (threadIdx.x >> 6);
    const int c = lane * 8;
    const size_t rb = (size_t)n * DIM + c;
    const float scale = 0.04419417382415922f;  // 1/sqrt(512)

    f32x4 tn_a, tn_b, sn_a, sn_b;
    bf8_to_f32(*(const u16x8*)(t_next + rb), tn_a, tn_b);
    bf8_to_f32(*(const u16x8*)(s_next + rb), sn_a, sn_b);

    // ---- phase-1 loads ----
    f32x4 p1s[NTAU][2], p1t[NTAU][2];
#pragma unroll
    for (int k = 0; k < NTAU; k++) {
        const size_t kb = ((size_t)k * NTOK + n) * DIM + c;
        p1s[k][0] = NTLOAD4(s_att + kb);
        p1s[k][1] = NTLOAD4(s_att + kb + 4);
        p1t[k][0] = NTLOAD4(t_spatial + kb);
        p1t[k][1] = NTLOAD4(t_spatial + kb + 4);
    }

    // ---- partial dots (consume phase-1, frees those regs) ----
    float dws[NTAU], dwt[NTAU];
#pragma unroll
    for (int k = 0; k < NTAU; k++) {
        f32x4 a0 = p1s[k][0], a1 = p1s[k][1];
        f32x4 b0 = p1t[k][0], b1 = p1t[k][1];
        dws[k] = a0[0]*sn_a[0]+a0[1]*sn_a[1]+a0[2]*sn_a[2]+a0[3]*sn_a[3]
               + a1[0]*sn_b[0]+a1[1]*sn_b[1]+a1[2]*sn_b[2]+a1[3]*sn_b[3];
        dwt[k] = b0[0]*tn_a[0]+b0[1]*tn_a[1]+b0[2]*tn_a[2]+b0[3]*tn_a[3]
               + b1[0]*tn_b[0]+b1[1]*tn_b[1]+b1[2]*tn_b[2]+b1[3]*tn_b[3];
    }

    // ---- phase-2 loads: ISSUE NOW, consume after reduce ----
    f32x4 p2t[NTAU][2], p2s[NTAU][2];
#pragma unroll
    for (int k = 0; k < NTAU; k++) {
        const size_t kb = ((size_t)k * NTOK + n) * DIM + c;
        p2t[k][0] = NTLOAD4(t_att + kb);
        p2t[k][1] = NTLOAD4(t_att + kb + 4);
        p2s[k][0] = NTLOAD4(s_spatial + kb);
        p2s[k][1] = NTLOAD4(s_spatial + kb + 4);
    }
    f32x4 Ta = *(const f32x4*)(T_t + rb);
    f32x4 Tb = *(const f32x4*)(T_t + rb + 4);
    f32x4 Sa = *(const f32x4*)(S_t + rb);
    f32x4 Sb = *(const f32x4*)(S_t + rb + 4);

    // ---- wave reduce (overlaps with in-flight phase-2 loads) ----
#pragma unroll
    for (int k = 0; k < NTAU; k++) {
        float v = dws[k];
#pragma unroll
        for (int off = 32; off; off >>= 1) v += __shfl_xor(v, off);
        dws[k] = v * scale;
        float u = dwt[k];
#pragma unroll
        for (int off = 32; off; off >>= 1) u += __shfl_xor(u, off);
        dwt[k] = u * scale;
    }

    float ws_[NTAU], wt_[NTAU];
    {
        float ms = fmaxf(fmaxf(dws[0], dws[1]), fmaxf(dws[2], dws[3]));
        float mt = fmaxf(fmaxf(dwt[0], dwt[1]), fmaxf(dwt[2], dwt[3]));
        float ssum = 0.f, tsum = 0.f;
#pragma unroll
        for (int k = 0; k < NTAU; k++) {
            ws_[k] = __expf(dws[k] - ms); ssum += ws_[k];
            wt_[k] = __expf(dwt[k] - mt); tsum += wt_[k];
        }
        float rs = 1.f / ssum, rt = 1.f / tsum;
#pragma unroll
        for (int k = 0; k < NTAU; k++) { ws_[k] *= rs; wt_[k] *= rt; }
    }

    // ---- consume phase-2: trend accumulation + gating ----
    f32x4 Tta = {0,0,0,0}, Ttb = {0,0,0,0}, Sta = {0,0,0,0}, Stb = {0,0,0,0};
#pragma unroll
    for (int k = 0; k < NTAU; k++) {
        float wk = ws_[k], vk = wt_[k];
#pragma unroll
        for (int e = 0; e < 4; e++) {
            Tta[e] += wk * p2t[k][0][e]; Ttb[e] += wk * p2t[k][1][e];
            Sta[e] += vk * p2s[k][0][e]; Stb[e] += vk * p2s[k][1][e];
        }
    }

    u16x8 oT, oS;
#pragma unroll
    for (int e = 0; e < 4; e++) {
        float gt_a = 1.f / (1.f + __expf(-tn_a[e]));
        float gt_b = 1.f / (1.f + __expf(-tn_b[e]));
        float gs_a = 1.f / (1.f + __expf(-sn_a[e]));
        float gs_b = 1.f / (1.f + __expf(-sn_b[e]));
        oT[e]     = f2bf(Ta[e] * gt_a + (1.f - gt_a) * Tta[e]);
        oT[4 + e] = f2bf(Tb[e] * gt_b + (1.f - gt_b) * Ttb[e]);
        oS[e]     = f2bf(Sa[e] * gs_a + (1.f - gs_a) * Sta[e]);
        oS[4 + e] = f2bf(Sb[e] * gs_b + (1.f - gs_b) * Stb[e]);
    }
    *(u16x8*)(Tf + rb) = oT;
    *(u16x8*)(Sf + rb) = oS;
}

// ---------------- K3: fused final GEMM + epilogue -> d_out ----------------
// XCD-locality swizzle: grid = 2048 blocks (16 j x 128 m); all 16 j-blocks of
// an m-stripe land on the SAME XCD -> Tf/Sf stripe stays in that XCD's L2.
__global__ __launch_bounds__(256, 2) void gemm_final(
    const unsigned short* __restrict__ Tf, const unsigned short* __restrict__ Sf,
    const unsigned short* __restrict__ Wt, const unsigned short* __restrict__ Ws,
    const float* __restrict__ bt, const float* __restrict__ bs,
    float* __restrict__ out)
{
    __shared__ unsigned short lT[128][40];
    __shared__ unsigned short lS[128][40];
    __shared__ unsigned short lW[6][32][40];
    const int tid = threadIdx.x;
    const int id = blockIdx.x + 16 * blockIdx.y;  // dispatch-linear, 0..2047
    const int xcd = id & 7;
    const int idx = id >> 3;                      // 0..255
    const int m0 = (xcd * 16 + (idx >> 4)) * 128;
    const int j0 = (idx & 15) * 32;
    const int lane = tid & 63;
    const int w = tid >> 6, wr = w >> 1, wc = w & 1;

    f32x4 acc[6][4];
#pragma unroll
    for (int g = 0; g < 6; g++)
#pragma unroll
        for (int i = 0; i < 4; i++) acc[g][i] = (f32x4){0.f, 0.f, 0.f, 0.f};

    const int arow = tid >> 2;        // 0..63
    const int acol = (tid & 3) * 8;   // bf16 col

    for (int k0 = 0; k0 < DIM; k0 += 32) {
#pragma unroll
        for (int i = 0; i < 2; i++) {
            int r = arow + 64 * i;
            *(u16x8*)&lT[r][acol] = *(const u16x8*)(Tf + (size_t)(m0 + r) * DIM + k0 + acol);
            *(u16x8*)&lS[r][acol] = *(const u16x8*)(Sf + (size_t)(m0 + r) * DIM + k0 + acol);
        }
#pragma unroll
        for (int i = 0; i < 3; i++) {
            int cidx = tid + 256 * i;       // 0..767
            int g = cidx >> 7;              // 6 tiles of 128 chunks
            int rr = (cidx >> 2) & 31;
            int ch = (cidx & 3) * 8;
            const unsigned short* src = (g < 3) ? Wt : Ws;
            int row = (g % 3) * DIM + j0 + rr;
            *(u16x8*)&lW[g][rr][ch] = *(const u16x8*)(src + (size_t)row * DIM + k0 + ch);
        }
        __syncthreads();

        bf16x8 aT[4], aS[4];
#pragma unroll
        for (int i = 0; i < 4; i++) {
            aT[i] = *(const bf16x8*)&lT[wr * 64 + i * 16 + (lane & 15)][(lane >> 4) * 8];
            aS[i] = *(const bf16x8*)&lS[wr * 64 + i * 16 + (lane & 15)][(lane >> 4) * 8];
        }
#pragma unroll
        for (int g = 0; g < 6; g++) {
            bf16x8 bw = *(const bf16x8*)&lW[g][wc * 16 + (lane & 15)][(lane >> 4) * 8];
#pragma unroll
            for (int i = 0; i < 4; i++)
                acc[g][i] = __builtin_amdgcn_mfma_f32_16x16x32_bf16(
                    (g < 3) ? aT[i] : aS[i], bw, acc[g][i], 0, 0, 0);
        }
        __syncthreads();
    }

    const int j = j0 + wc * 16 + (lane & 15);
    const float btg = bt[j], btt = bt[512 + j], bts = bt[1024 + j];
    const float bsg = bs[j], bst = bs[512 + j], bss = bs[1024 + j];
#pragma unroll
    for (int i = 0; i < 4; i++) {
        int mbase = m0 + wr * 64 + i * 16 + (lane >> 4) * 4;
#pragma unroll
        for (int r = 0; r < 4; r++) {
            float TG = acc[0][i][r] + btg;
            float TT = acc[1][i][r] + btt;
            float TS = acc[2][i][r] + bts;
            float SG = acc[3][i][r] + bsg;
            float ST = acc[4][i][r] + bst;
            float SS = acc[5][i][r] + bss;
            float gT = 1.f / (1.f + __expf(-TG));
            float gS = 1.f / (1.f + __expf(-SG));
            size_t m = (size_t)(mbase + r);
            out[m * DIM + j] = gT * TT + (1.f - gT) * ST;
            out[(size_t)NTOK * DIM + m * DIM + j] = gS * SS + (1.f - gS) * TS;
        }
    }
}

extern "C" void kernel_launch(void* const* d_in, const int* in_sizes, int n_in,
                              void* d_out, int out_size, void* d_ws, size_t ws_size,
                              hipStream_t stream) {
    const float* T_t       = (const float*)d_in[0];
    const float* S_t       = (const float*)d_in[1];
    const float* t_att     = (const float*)d_in[2];
    const float* s_att     = (const float*)d_in[3];
    const float* t_spatial = (const float*)d_in[4];
    const float* s_spatial = (const float*)d_in[5];
    const float* W_t  = (const float*)d_in[6];
    const float* b_t  = (const float*)d_in[7];
    const float* W_tn = (const float*)d_in[8];
    const float* b_tn = (const float*)d_in[9];
    const float* W_s  = (const float*)d_in[10];
    const float* b_s  = (const float*)d_in[11];
    const float* W_sn = (const float*)d_in[12];
    const float* b_sn = (const float*)d_in[13];
    float* out = (float*)d_out;

    char* ws = (char*)d_ws;
    unsigned short* t_next = (unsigned short*)(ws + 0);          // 16.8 MB
    unsigned short* s_next = (unsigned short*)(ws + 16777216);
    unsigned short* Tf     = (unsigned short*)(ws + 33554432);
    unsigned short* Sf     = (unsigned short*)(ws + 50331648);
    unsigned short* Wtn_b  = (unsigned short*)(ws + 67108864);
    unsigned short* Wsn_b  = (unsigned short*)(ws + 67633152);
    unsigned short* Wt_b   = (unsigned short*)(ws + 68157440);
    unsigned short* Ws_b   = (unsigned short*)(ws + 69730304);

    const int n_sq = 512 * 512 / 4, n_big = 1536 * 512 / 4;
    convert_f32_bf16<<<(n_sq + 255) / 256, 256, 0, stream>>>(W_tn, Wtn_b, n_sq);
    convert_f32_bf16<<<(n_sq + 255) / 256, 256, 0, stream>>>(W_sn, Wsn_b, n_sq);
    convert_f32_bf16<<<(n_big + 255) / 256, 256, 0, stream>>>(W_t, Wt_b, n_big);
    convert_f32_bf16<<<(n_big + 255) / 256, 256, 0, stream>>>(W_s, Ws_b, n_big);

    dim3 g1(DIM / 128, NTOK / 128);
    gemm_next<<<g1, 256, 0, stream>>>(T_t, Wtn_b, b_tn, t_next);
    gemm_next<<<g1, 256, 0, stream>>>(S_t, Wsn_b, b_sn, s_next);

    fuse_stream<<<4096, 256, 0, stream>>>(T_t, S_t, t_att, s_att, t_spatial, s_spatial,
                                          t_next, s_next, Tf, Sf);

    dim3 g3(DIM / 32, NTOK / 128);
    gemm_final<<<g3, 256, 0, stream>>>(Tf, Sf, Wt_b, Ws_b, b_t, b_s, out);
}

// Round 4
// 288.178 us; speedup vs baseline: 1.0610x; 1.0149x over previous
//
#include <hip/hip_runtime.h>

#define NTOK 16384
#define DIM 512
#define NTAU 4

typedef __attribute__((ext_vector_type(4))) float f32x4;
typedef __attribute__((ext_vector_type(8))) short bf16x8;   // 8 bf16 in 4 VGPRs
typedef __attribute__((ext_vector_type(4))) unsigned short u16x4;
typedef __attribute__((ext_vector_type(8))) unsigned short u16x8;
typedef unsigned int u32;

__device__ inline unsigned short f2bf(float f) {
    union { float f; unsigned int u; } v; v.f = f;
    unsigned int u = v.u + 0x7FFFu + ((v.u >> 16) & 1u);  // RNE
    return (unsigned short)(u >> 16);
}

__device__ inline void bf8_to_f32(u16x8 h, f32x4& a, f32x4& b) {
    union { unsigned int u; float f; } t;
#pragma unroll
    for (int e = 0; e < 4; e++) { t.u = ((unsigned int)h[e]) << 16; a[e] = t.f; }
#pragma unroll
    for (int e = 0; e < 4; e++) { t.u = ((unsigned int)h[4 + e]) << 16; b[e] = t.f; }
}

#define NTLOAD4(p) __builtin_nontemporal_load((const f32x4*)(p))

// async global -> LDS, 16 bytes per lane. LDS dest: wave-uniform base + lane*16.
__device__ __forceinline__ void gload16(const void* g, void* l) {
    __builtin_amdgcn_global_load_lds((const __attribute__((address_space(1))) u32*)g,
                                     (__attribute__((address_space(3))) u32*)l, 16, 0, 0);
}

// ---------------- K0: fp32 -> bf16 convert (all 4 weight mats, one launch) ----
__global__ void convert_all(const float* __restrict__ a, const float* __restrict__ b,
                            const float* __restrict__ c, const float* __restrict__ d,
                            unsigned short* __restrict__ oa, unsigned short* __restrict__ ob,
                            unsigned short* __restrict__ oc, unsigned short* __restrict__ od) {
    int i = blockIdx.x * 256 + threadIdx.x;   // 0..524287 (x4 units)
    const float* s; unsigned short* t; int off;
    if (i < 65536)       { s = a; t = oa; off = i; }
    else if (i < 131072) { s = b; t = ob; off = i - 65536; }
    else if (i < 327680) { s = c; t = oc; off = i - 131072; }
    else                 { s = d; t = od; off = i - 327680; }
    f32x4 v = ((const f32x4*)s)[off];
    u16x4 o;
    o[0] = f2bf(v[0]); o[1] = f2bf(v[1]); o[2] = f2bf(v[2]); o[3] = f2bf(v[3]);
    ((u16x4*)t)[off] = o;
}

// ---------------- K1: next = A @ W^T + b  -> bf16 out ----------------
__global__ __launch_bounds__(256, 2) void gemm_next(
    const float* __restrict__ A, const unsigned short* __restrict__ W,
    const float* __restrict__ bias, unsigned short* __restrict__ out)
{
    __shared__ unsigned short lA[128][40];
    __shared__ unsigned short lB[128][40];
    const int tid = threadIdx.x;
    const int id = blockIdx.x + 4 * blockIdx.y;   // 0..511
    const int xcd = id & 7;
    const int idx = id >> 3;
    const int m0 = (xcd * 16 + (idx >> 2)) * 128;
    const int n0 = (idx & 3) * 128;
    const int lane = tid & 63;
    const int w = tid >> 6;
    const int wr = w >> 1, wc = w & 1;

    f32x4 acc[4][4];
#pragma unroll
    for (int i = 0; i < 4; i++)
#pragma unroll
        for (int j = 0; j < 4; j++) acc[i][j] = (f32x4){0.f, 0.f, 0.f, 0.f};

    const int arow = tid >> 3;
    const int acol = (tid & 7) * 4;
    const int brow = tid >> 2;
    const int bcol = (tid & 3) * 8;

    for (int k0 = 0; k0 < DIM; k0 += 32) {
#pragma unroll
        for (int i = 0; i < 4; i++) {
            int r = arow + 32 * i;
            f32x4 v = *(const f32x4*)(A + (size_t)(m0 + r) * DIM + k0 + acol);
            u16x4 o;
            o[0] = f2bf(v[0]); o[1] = f2bf(v[1]); o[2] = f2bf(v[2]); o[3] = f2bf(v[3]);
            *(u16x4*)&lA[r][acol] = o;
        }
#pragma unroll
        for (int i = 0; i < 2; i++) {
            int r = brow + 64 * i;
            u16x8 v = *(const u16x8*)(W + (size_t)(n0 + r) * DIM + k0 + bcol);
            *(u16x8*)&lB[r][bcol] = v;
        }
        __syncthreads();

        bf16x8 af[4], bfr[4];
#pragma unroll
        for (int i = 0; i < 4; i++)
            af[i] = *(const bf16x8*)&lA[wr * 64 + i * 16 + (lane & 15)][(lane >> 4) * 8];
#pragma unroll
        for (int j = 0; j < 4; j++)
            bfr[j] = *(const bf16x8*)&lB[wc * 64 + j * 16 + (lane & 15)][(lane >> 4) * 8];
#pragma unroll
        for (int i = 0; i < 4; i++)
#pragma unroll
            for (int j = 0; j < 4; j++)
                acc[i][j] = __builtin_amdgcn_mfma_f32_16x16x32_bf16(af[i], bfr[j], acc[i][j], 0, 0, 0);
        __syncthreads();
    }

#pragma unroll
    for (int j = 0; j < 4; j++) {
        int n = n0 + wc * 64 + j * 16 + (lane & 15);
        float bv = bias[n];
#pragma unroll
        for (int i = 0; i < 4; i++) {
            int mbase = m0 + wr * 64 + i * 16 + (lane >> 4) * 4;
#pragma unroll
            for (int r = 0; r < 4; r++)
                out[(size_t)(mbase + r) * DIM + n] = f2bf(acc[i][j][r] + bv);
        }
    }
}

// ---------------- K2: streaming fuse — ALL loads upfront (max per-wave MLP) ----
__global__ __launch_bounds__(256) void fuse_stream(
    const float* __restrict__ T_t, const float* __restrict__ S_t,
    const float* __restrict__ t_att, const float* __restrict__ s_att,
    const float* __restrict__ t_spatial, const float* __restrict__ s_spatial,
    const unsigned short* __restrict__ t_next, const unsigned short* __restrict__ s_next,
    unsigned short* __restrict__ Tf, unsigned short* __restrict__ Sf)
{
    const int lane = threadIdx.x & 63;
    const int n = (blockIdx.x << 2) + (threadIdx.x >> 6);
    const int c = lane * 8;
    const size_t rb = (size_t)n * DIM + c;
    const float scale = 0.04419417382415922f;  // 1/sqrt(512)

    // ---- issue EVERY load before any dependent compute ----
    u16x8 hn_t = *(const u16x8*)(t_next + rb);
    u16x8 hn_s = *(const u16x8*)(s_next + rb);
    f32x4 p1s[NTAU][2], p1t[NTAU][2], p2t[NTAU][2], p2s[NTAU][2];
#pragma unroll
    for (int k = 0; k < NTAU; k++) {
        const size_t kb = ((size_t)k * NTOK + n) * DIM + c;
        p1s[k][0] = NTLOAD4(s_att + kb);
        p1s[k][1] = NTLOAD4(s_att + kb + 4);
        p1t[k][0] = NTLOAD4(t_spatial + kb);
        p1t[k][1] = NTLOAD4(t_spatial + kb + 4);
    }
#pragma unroll
    for (int k = 0; k < NTAU; k++) {
        const size_t kb = ((size_t)k * NTOK + n) * DIM + c;
        p2t[k][0] = NTLOAD4(t_att + kb);
        p2t[k][1] = NTLOAD4(t_att + kb + 4);
        p2s[k][0] = NTLOAD4(s_spatial + kb);
        p2s[k][1] = NTLOAD4(s_spatial + kb + 4);
    }
    f32x4 Ta = *(const f32x4*)(T_t + rb);
    f32x4 Tb = *(const f32x4*)(T_t + rb + 4);
    f32x4 Sa = *(const f32x4*)(S_t + rb);
    f32x4 Sb = *(const f32x4*)(S_t + rb + 4);

    f32x4 tn_a, tn_b, sn_a, sn_b;
    bf8_to_f32(hn_t, tn_a, tn_b);
    bf8_to_f32(hn_s, sn_a, sn_b);

    float dws[NTAU], dwt[NTAU];
#pragma unroll
    for (int k = 0; k < NTAU; k++) {
        f32x4 a0 = p1s[k][0], a1 = p1s[k][1];
        f32x4 b0 = p1t[k][0], b1 = p1t[k][1];
        dws[k] = a0[0]*sn_a[0]+a0[1]*sn_a[1]+a0[2]*sn_a[2]+a0[3]*sn_a[3]
               + a1[0]*sn_b[0]+a1[1]*sn_b[1]+a1[2]*sn_b[2]+a1[3]*sn_b[3];
        dwt[k] = b0[0]*tn_a[0]+b0[1]*tn_a[1]+b0[2]*tn_a[2]+b0[3]*tn_a[3]
               + b1[0]*tn_b[0]+b1[1]*tn_b[1]+b1[2]*tn_b[2]+b1[3]*tn_b[3];
    }
#pragma unroll
    for (int k = 0; k < NTAU; k++) {
        float v = dws[k];
#pragma unroll
        for (int off = 32; off; off >>= 1) v += __shfl_xor(v, off);
        dws[k] = v * scale;
        float u = dwt[k];
#pragma unroll
        for (int off = 32; off; off >>= 1) u += __shfl_xor(u, off);
        dwt[k] = u * scale;
    }

    float ws_[NTAU], wt_[NTAU];
    {
        float ms = fmaxf(fmaxf(dws[0], dws[1]), fmaxf(dws[2], dws[3]));
        float mt = fmaxf(fmaxf(dwt[0], dwt[1]), fmaxf(dwt[2], dwt[3]));
        float ssum = 0.f, tsum = 0.f;
#pragma unroll
        for (int k = 0; k < NTAU; k++) {
            ws_[k] = __expf(dws[k] - ms); ssum += ws_[k];
            wt_[k] = __expf(dwt[k] - mt); tsum += wt_[k];
        }
        float rs = 1.f / ssum, rt = 1.f / tsum;
#pragma unroll
        for (int k = 0; k < NTAU; k++) { ws_[k] *= rs; wt_[k] *= rt; }
    }

    f32x4 Tta = {0,0,0,0}, Ttb = {0,0,0,0}, Sta = {0,0,0,0}, Stb = {0,0,0,0};
#pragma unroll
    for (int k = 0; k < NTAU; k++) {
        float wk = ws_[k], vk = wt_[k];
#pragma unroll
        for (int e = 0; e < 4; e++) {
            Tta[e] += wk * p2t[k][0][e]; Ttb[e] += wk * p2t[k][1][e];
            Sta[e] += vk * p2s[k][0][e]; Stb[e] += vk * p2s[k][1][e];
        }
    }

    u16x8 oT, oS;
#pragma unroll
    for (int e = 0; e < 4; e++) {
        float gt_a = 1.f / (1.f + __expf(-tn_a[e]));
        float gt_b = 1.f / (1.f + __expf(-tn_b[e]));
        float gs_a = 1.f / (1.f + __expf(-sn_a[e]));
        float gs_b = 1.f / (1.f + __expf(-sn_b[e]));
        oT[e]     = f2bf(Ta[e] * gt_a + (1.f - gt_a) * Tta[e]);
        oT[4 + e] = f2bf(Tb[e] * gt_b + (1.f - gt_b) * Ttb[e]);
        oS[e]     = f2bf(Sa[e] * gs_a + (1.f - gs_a) * Sta[e]);
        oS[4 + e] = f2bf(Sb[e] * gs_b + (1.f - gs_b) * Stb[e]);
    }
    *(u16x8*)(Tf + rb) = oT;
    *(u16x8*)(Sf + rb) = oS;
}

// ---------------- K3: fused final GEMM, m97-structure ----------------
// global_load_lds(16B) staging, double-buffered linear LDS, granule XOR swizzle
// g ^= (row>>1)&3 applied on BOTH the per-lane global source and the ds_read.
__global__ __launch_bounds__(256, 2) void gemm_final(
    const unsigned short* __restrict__ Tf, const unsigned short* __restrict__ Sf,
    const unsigned short* __restrict__ Wt, const unsigned short* __restrict__ Ws,
    const float* __restrict__ bt, const float* __restrict__ bs,
    float* __restrict__ out)
{
    __shared__ __align__(16) unsigned short lT[2][128][32];
    __shared__ __align__(16) unsigned short lS[2][128][32];
    __shared__ __align__(16) unsigned short lW[2][192][32];
    const int tid = threadIdx.x;
    const int id = blockIdx.x + 16 * blockIdx.y;  // 0..2047
    const int xcd = id & 7;
    const int idx = id >> 3;
    const int m0 = (xcd * 16 + (idx >> 4)) * 128;
    const int j0 = (idx & 15) * 32;
    const int lane = tid & 63;
    const int w = tid >> 6, wr = w >> 1, wc = w & 1;

    f32x4 acc[6][4];
#pragma unroll
    for (int g = 0; g < 6; g++)
#pragma unroll
        for (int i = 0; i < 4; i++) acc[g][i] = (f32x4){0.f, 0.f, 0.f, 0.f};

    const int srow = lane >> 2;   // staging: row-within-16
    const int sg   = lane & 3;    // staging: physical granule

    // waves 0,1: stage lT+lS (64 rows each); waves 2,3: stage lW (96 rows each)
    auto stage = [&](int buf, int kt) {
        const int k0 = kt * 32;
        if (w < 2) {
            const int rbs = w * 64;
#pragma unroll
            for (int i = 0; i < 4; i++) {
                const int row = rbs + i * 16 + srow;
                const int lg = sg ^ ((row >> 1) & 3);        // logical granule
                gload16(Tf + (size_t)(m0 + row) * DIM + k0 + lg * 8, &lT[buf][rbs + i * 16][0]);
                gload16(Sf + (size_t)(m0 + row) * DIM + k0 + lg * 8, &lS[buf][rbs + i * 16][0]);
            }
        } else {
            const int rbs = (w - 2) * 96;
#pragma unroll
            for (int i = 0; i < 6; i++) {
                const int r = rbs + i * 16 + srow;           // 0..191
                const int lg = sg ^ ((r >> 1) & 3);
                const int g = r >> 5;
                const unsigned short* src = (g < 3) ? Wt : Ws;
                const int wrow = (g < 3 ? g : g - 3) * DIM + j0 + (r & 31);
                gload16(src + (size_t)wrow * DIM + k0 + lg * 8, &lW[buf][rbs + i * 16][0]);
            }
        }
    };

    stage(0, 0);
    __syncthreads();   // drains vmcnt -> buf0 ready

    int cur = 0;
    for (int kt = 0; kt < 16; ++kt) {
        if (kt < 15) stage(cur ^ 1, kt + 1);   // overlaps with MFMA below

        bf16x8 aT[4], aS[4];
#pragma unroll
        for (int i = 0; i < 4; i++) {
            const int row = wr * 64 + i * 16 + (lane & 15);
            const int pg = (lane >> 4) ^ ((row >> 1) & 3);
            aT[i] = *(const bf16x8*)&lT[cur][row][pg * 8];
            aS[i] = *(const bf16x8*)&lS[cur][row][pg * 8];
        }
#pragma unroll
        for (int g = 0; g < 6; g++) {
            const int r = g * 32 + wc * 16 + (lane & 15);
            const int pg = (lane >> 4) ^ ((r >> 1) & 3);
            bf16x8 bw = *(const bf16x8*)&lW[cur][r][pg * 8];
#pragma unroll
            for (int i = 0; i < 4; i++)
                acc[g][i] = __builtin_amdgcn_mfma_f32_16x16x32_bf16(
                    (g < 3) ? aT[i] : aS[i], bw, acc[g][i], 0, 0, 0);
        }
        __syncthreads();   // drains vmcnt (staging done) + all reads of cur done
        cur ^= 1;
    }

    const int j = j0 + wc * 16 + (lane & 15);
    const float btg = bt[j], btt = bt[512 + j], bts = bt[1024 + j];
    const float bsg = bs[j], bst = bs[512 + j], bss = bs[1024 + j];
#pragma unroll
    for (int i = 0; i < 4; i++) {
        int mbase = m0 + wr * 64 + i * 16 + (lane >> 4) * 4;
#pragma unroll
        for (int r = 0; r < 4; r++) {
            float TG = acc[0][i][r] + btg;
            float TT = acc[1][i][r] + btt;
            float TS = acc[2][i][r] + bts;
            float SG = acc[3][i][r] + bsg;
            float ST = acc[4][i][r] + bst;
            float SS = acc[5][i][r] + bss;
            float gT = 1.f / (1.f + __expf(-TG));
            float gS = 1.f / (1.f + __expf(-SG));
            size_t m = (size_t)(mbase + r);
            out[m * DIM + j] = gT * TT + (1.f - gT) * ST;
            out[(size_t)NTOK * DIM + m * DIM + j] = gS * SS + (1.f - gS) * TS;
        }
    }
}

extern "C" void kernel_launch(void* const* d_in, const int* in_sizes, int n_in,
                              void* d_out, int out_size, void* d_ws, size_t ws_size,
                              hipStream_t stream) {
    const float* T_t       = (const float*)d_in[0];
    const float* S_t       = (const float*)d_in[1];
    const float* t_att     = (const float*)d_in[2];
    const float* s_att     = (const float*)d_in[3];
    const float* t_spatial = (const float*)d_in[4];
    const float* s_spatial = (const float*)d_in[5];
    const float* W_t  = (const float*)d_in[6];
    const float* b_t  = (const float*)d_in[7];
    const float* W_tn = (const float*)d_in[8];
    const float* b_tn = (const float*)d_in[9];
    const float* W_s  = (const float*)d_in[10];
    const float* b_s  = (const float*)d_in[11];
    const float* W_sn = (const float*)d_in[12];
    const float* b_sn = (const float*)d_in[13];
    float* out = (float*)d_out;

    char* ws = (char*)d_ws;
    unsigned short* t_next = (unsigned short*)(ws + 0);          // 16.8 MB
    unsigned short* s_next = (unsigned short*)(ws + 16777216);
    unsigned short* Tf     = (unsigned short*)(ws + 33554432);
    unsigned short* Sf     = (unsigned short*)(ws + 50331648);
    unsigned short* Wtn_b  = (unsigned short*)(ws + 67108864);
    unsigned short* Wsn_b  = (unsigned short*)(ws + 67633152);
    unsigned short* Wt_b   = (unsigned short*)(ws + 68157440);
    unsigned short* Ws_b   = (unsigned short*)(ws + 69730304);

    // one launch converts all 4 weight matrices (524288 x4-units)
    convert_all<<<2048, 256, 0, stream>>>(W_tn, W_sn, W_t, W_s,
                                          Wtn_b, Wsn_b, Wt_b, Ws_b);

    dim3 g1(DIM / 128, NTOK / 128);
    gemm_next<<<g1, 256, 0, stream>>>(T_t, Wtn_b, b_tn, t_next);
    gemm_next<<<g1, 256, 0, stream>>>(S_t, Wsn_b, b_sn, s_next);

    fuse_stream<<<4096, 256, 0, stream>>>(T_t, S_t, t_att, s_att, t_spatial, s_spatial,
                                          t_next, s_next, Tf, Sf);

    dim3 g3(DIM / 32, NTOK / 128);
    gemm_final<<<g3, 256, 0, stream>>>(Tf, Sf, Wt_b, Ws_b, b_t, b_s, out);
}